// Round 10
// baseline (448.572 us; speedup 1.0000x reference)
//
#include <hip/hip_runtime.h>
#include <math.h>

#define NEG 0.2f

__device__ __forceinline__ float leaky(float x){ return x >= 0.f ? x : NEG*x; }

__device__ __forceinline__ unsigned short f2b(float f){
    unsigned u = __float_as_uint(f);
    unsigned r = u + 0x7fffu + ((u >> 16) & 1u);
    return (unsigned short)(r >> 16);
}

// ---------------- CSR build: ONE atomic pass, 4 edges/thread (ILP) ---------
__global__ void k_rank(const int* __restrict__ ei, int* __restrict__ cnt,
                       int* __restrict__ rank, int E, int ET){
    int i0 = (blockIdx.x*256 + threadIdx.x)*4;
    if (i0 >= ET) return;
    int4 r;
    if (i0 + 3 < E){
        int4 d4 = *(const int4*)(ei + E + i0);
        r.x = atomicAdd(&cnt[d4.x], 1);
        r.y = atomicAdd(&cnt[d4.y], 1);
        r.z = atomicAdd(&cnt[d4.z], 1);
        r.w = atomicAdd(&cnt[d4.w], 1);
    } else {
        #pragma unroll
        for (int u = 0; u < 4; ++u){
            int i = i0 + u;
            int dst = (i < E) ? ei[E + i] : (i - E);
            ((int*)&r)[u] = atomicAdd(&cnt[dst], 1);
        }
    }
    *(int4*)(rank + i0) = r;   // ET is a multiple of 4 in practice; guarded by grid
}
__global__ void k_scan1(const int* __restrict__ cnt, int* __restrict__ bsum, int n){
    __shared__ int sh[256];
    int b = blockIdx.x, tid = threadIdx.x;
    int start = b*1024, s = 0;
    for (int i = tid; i < 1024; i += 256){ int idx = start+i; s += (idx<n)?cnt[idx]:0; }
    sh[tid]=s; __syncthreads();
    for (int d=128; d>0; d>>=1){ if (tid<d) sh[tid]+=sh[tid+d]; __syncthreads(); }
    if (tid==0) bsum[b]=sh[0];
}
__global__ void k_scan2(int* bsum, int nb){
    if (threadIdx.x==0 && blockIdx.x==0){
        int run=0;
        for (int i=0;i<nb;i++){ int v=bsum[i]; bsum[i]=run; run+=v; }
    }
}
__global__ void k_scan3(const int* __restrict__ cnt, const int* __restrict__ bsum,
                        int* __restrict__ rowptr, int n){
    __shared__ int sh[256];
    int b = blockIdx.x, tid = threadIdx.x;
    int i0 = b*1024 + tid*4;
    int v[4]; int local=0;
    #pragma unroll
    for (int k=0;k<4;k++){ int idx=i0+k; v[k]=(idx<n)?cnt[idx]:0; local+=v[k]; }
    sh[tid]=local; __syncthreads();
    for (int d=1; d<256; d<<=1){
        int t = (tid>=d)? sh[tid-d] : 0;
        __syncthreads();
        sh[tid] += t;
        __syncthreads();
    }
    int off = bsum[b] + sh[tid] - local;
    #pragma unroll
    for (int k=0;k<4;k++){
        int idx = i0+k;
        if (idx < n){
            rowptr[idx]=off; off += v[k];
            if (idx==n-1) rowptr[n]=off;
        }
    }
}

// ---------------- score: edge-parallel p = exp(leaky(s[src]+d[dst])),
// packed {src, p_bits} scattered into CSR slot rowptr[dst]+rank[i].
__global__ void k_score(const int* __restrict__ ei, const int* __restrict__ rank,
                        const int* __restrict__ rowptr,
                        const float* __restrict__ s, const float* __restrict__ d,
                        int2* __restrict__ csrp, int E, int ET){
    int i = blockIdx.x*256 + threadIdx.x;
    if (i >= ET) return;
    int src = (i < E) ? ei[i]     : (i - E);
    int dst = (i < E) ? ei[E + i] : (i - E);
    float pv = expf(leaky(s[src] + d[dst]));
    csrp[rowptr[dst] + rank[i]] = make_int2(src, __float_as_int(pv));
}

// ---------------- g1: outer-product register-tile GEMM -------------------
__global__ __launch_bounds__(256) void g1(const float* __restrict__ x,
        const float* __restrict__ W1, const float* __restrict__ a_src,
        const float* __restrict__ a_dst, unsigned short* __restrict__ h1b,
        float* __restrict__ s1, float* __restrict__ d1, int N)
{
    __shared__ float xsh[64][132];
    __shared__ float wsh[128][64];
    const int tid = threadIdx.x;
    const int rowbase = blockIdx.x * 64;
    #pragma unroll
    for (int i = 0; i < 8; ++i){
        int g = tid + i*256;
        ((float4*)&wsh[0][0])[g] = ((const float4*)W1)[g];
    }
    #pragma unroll
    for (int i = 0; i < 8; ++i){
        int g = tid + i*256;
        int r = g >> 5, c4 = g & 31;
        int grow = rowbase + r;
        float4 v = make_float4(0.f,0.f,0.f,0.f);
        if (grow < N) v = ((const float4*)(x + (size_t)grow*128))[c4];
        *(float4*)&xsh[r][c4*4] = v;
    }
    __syncthreads();
    const int tx = tid & 15, ty = tid >> 4;
    float acc[4][4];
    #pragma unroll
    for (int j=0;j<4;++j){
        #pragma unroll
        for (int c=0;c<4;++c) acc[j][c]=0.f;
    }
    #pragma unroll 4
    for (int k4 = 0; k4 < 32; ++k4){
        float4 xv[4], wv[4];
        #pragma unroll
        for (int j=0;j<4;++j) xv[j] = *(const float4*)&xsh[ty*4+j][k4*4];
        #pragma unroll
        for (int i=0;i<4;++i) wv[i] = *(const float4*)&wsh[k4*4+i][tx*4];
        #pragma unroll
        for (int j=0;j<4;++j){
            float x0=xv[j].x, x1=xv[j].y, x2=xv[j].z, x3=xv[j].w;
            acc[j][0]=fmaf(x0,wv[0].x,acc[j][0]); acc[j][1]=fmaf(x0,wv[0].y,acc[j][1]);
            acc[j][2]=fmaf(x0,wv[0].z,acc[j][2]); acc[j][3]=fmaf(x0,wv[0].w,acc[j][3]);
            acc[j][0]=fmaf(x1,wv[1].x,acc[j][0]); acc[j][1]=fmaf(x1,wv[1].y,acc[j][1]);
            acc[j][2]=fmaf(x1,wv[1].z,acc[j][2]); acc[j][3]=fmaf(x1,wv[1].w,acc[j][3]);
            acc[j][0]=fmaf(x2,wv[2].x,acc[j][0]); acc[j][1]=fmaf(x2,wv[2].y,acc[j][1]);
            acc[j][2]=fmaf(x2,wv[2].z,acc[j][2]); acc[j][3]=fmaf(x2,wv[2].w,acc[j][3]);
            acc[j][0]=fmaf(x3,wv[3].x,acc[j][0]); acc[j][1]=fmaf(x3,wv[3].y,acc[j][1]);
            acc[j][2]=fmaf(x3,wv[3].z,acc[j][2]); acc[j][3]=fmaf(x3,wv[3].w,acc[j][3]);
        }
    }
    const float4 asv = *(const float4*)&a_src[tx*4];
    const float4 adv = *(const float4*)&a_dst[tx*4];
    #pragma unroll
    for (int j=0;j<4;++j){
        int r = rowbase + ty*4 + j;
        float sv = acc[j][0]*asv.x + acc[j][1]*asv.y + acc[j][2]*asv.z + acc[j][3]*asv.w;
        float dv = acc[j][0]*adv.x + acc[j][1]*adv.y + acc[j][2]*adv.z + acc[j][3]*adv.w;
        #pragma unroll
        for (int dd=8; dd>0; dd>>=1){ sv += __shfl_xor(sv, dd, 16); dv += __shfl_xor(dv, dd, 16); }
        if (r < N){
            uint2 pk;
            pk.x = (unsigned)f2b(acc[j][0]) | ((unsigned)f2b(acc[j][1]) << 16);
            pk.y = (unsigned)f2b(acc[j][2]) | ((unsigned)f2b(acc[j][3]) << 16);
            *(uint2*)&h1b[(size_t)r*64 + tx*4] = pk;
            if (tx == 0){ s1[r] = sv; d1[r] = dv; }
        }
    }
}

// ---------------- a1: aggregate layer 1, 8 edge-slots x 8 channel-groups ---
__global__ __launch_bounds__(256) void a1(const int* __restrict__ rowptr,
        const int2* __restrict__ csrp, const unsigned short* __restrict__ h1b,
        const float* __restrict__ b1, float* __restrict__ out1, int N)
{
    int wid = threadIdx.x>>6, lane = threadIdx.x&63;
    int n = blockIdx.x*4 + wid;
    if (n >= N) return;
    int base = rowptr[n], end = rowptr[n+1];
    int es = lane >> 3, cg = lane & 7;
    float a0=0.f,a1v=0.f,a2v=0.f,a3=0.f,a4=0.f,a5=0.f,a6=0.f,a7=0.f;
    float z = 0.f;
    for (int k = base + es; k < end; k += 8){
        int2 cp = csrp[k];
        float pv = __int_as_float(cp.y);
        z += pv;
        uint4 hv = *(const uint4*)(h1b + (size_t)cp.x*64 + cg*8);
        a0 = fmaf(pv, __uint_as_float(hv.x << 16),          a0);
        a1v= fmaf(pv, __uint_as_float(hv.x & 0xffff0000u),  a1v);
        a2v= fmaf(pv, __uint_as_float(hv.y << 16),          a2v);
        a3 = fmaf(pv, __uint_as_float(hv.y & 0xffff0000u),  a3);
        a4 = fmaf(pv, __uint_as_float(hv.z << 16),          a4);
        a5 = fmaf(pv, __uint_as_float(hv.z & 0xffff0000u),  a5);
        a6 = fmaf(pv, __uint_as_float(hv.w << 16),          a6);
        a7 = fmaf(pv, __uint_as_float(hv.w & 0xffff0000u),  a7);
    }
    #pragma unroll
    for (int m = 8; m <= 32; m <<= 1){
        a0 += __shfl_xor(a0, m); a1v += __shfl_xor(a1v, m);
        a2v += __shfl_xor(a2v, m); a3 += __shfl_xor(a3, m);
        a4 += __shfl_xor(a4, m); a5 += __shfl_xor(a5, m);
        a6 += __shfl_xor(a6, m); a7 += __shfl_xor(a7, m);
        z  += __shfl_xor(z, m);
    }
    if (es == 0){
        float zi = 1.f/(z + 1e-16f);
        const float4 b0 = *(const float4*)(b1 + cg*8);
        const float4 b4 = *(const float4*)(b1 + cg*8 + 4);
        float4 o0 = make_float4(fmaxf(a0*zi + b0.x, 0.f), fmaxf(a1v*zi + b0.y, 0.f),
                                fmaxf(a2v*zi + b0.z, 0.f), fmaxf(a3*zi + b0.w, 0.f));
        float4 o4 = make_float4(fmaxf(a4*zi + b4.x, 0.f), fmaxf(a5*zi + b4.y, 0.f),
                                fmaxf(a6*zi + b4.z, 0.f), fmaxf(a7*zi + b4.w, 0.f));
        float* op = out1 + (size_t)n*64 + cg*8;
        *(float4*)op = o0;
        *(float4*)(op+4) = o4;
    }
}

// ---------------- g2: h2b(bf16) = out1 @ W2; s2; d2 ------------------------
__global__ __launch_bounds__(256) void g2(const float* __restrict__ xin,
        const float* __restrict__ W2, const float* __restrict__ a_src,
        const float* __restrict__ a_dst, unsigned short* __restrict__ h2b,
        float* __restrict__ s2, float* __restrict__ d2, int N)
{
    __shared__ float w[64*16];
    const int tid = threadIdx.x;
    for (int k = tid; k < 64*16/4; k += 256)
        ((float4*)w)[k] = ((const float4*)W2)[k];
    __syncthreads();
    int idx = blockIdx.x*256 + tid;
    int n = idx >> 4, c = idx & 15;
    if (n >= N) return;
    const float as = a_src[c], ad = a_dst[c];
    const float4* xr = (const float4*)(xin + (size_t)n*64);
    float acc = 0.f;
    #pragma unroll
    for (int i4 = 0; i4 < 16; ++i4) {
        float4 v = xr[i4];
        acc = fmaf(v.x, w[(i4*4+0)*16 + c], acc);
        acc = fmaf(v.y, w[(i4*4+1)*16 + c], acc);
        acc = fmaf(v.z, w[(i4*4+2)*16 + c], acc);
        acc = fmaf(v.w, w[(i4*4+3)*16 + c], acc);
    }
    h2b[(size_t)n*16 + c] = f2b(acc);
    float sv = acc*as, dv = acc*ad;
    #pragma unroll
    for (int dd = 8; dd > 0; dd >>= 1){ sv += __shfl_xor(sv, dd, 16); dv += __shfl_xor(dv, dd, 16); }
    if (c == 0) { s2[n] = sv; d2[n] = dv; }
}

// ---------------- a2: aggregate layer 2 + log_softmax ----------------------
// lane = es*2+cg: 32 edge-slots x 2 half-rows; lane loads ushort8 (16B) =
// channels cg*8..cg*8+7 -> 1KB = 32 h2-rows per gather instruction.
__global__ __launch_bounds__(256) void a2(const int* __restrict__ rowptr,
        const int2* __restrict__ csrp, const unsigned short* __restrict__ h2b,
        const float* __restrict__ b2, float* __restrict__ out, int N)
{
    int wid = threadIdx.x>>6, lane = threadIdx.x&63;
    int n = blockIdx.x*4 + wid;
    if (n >= N) return;
    int base = rowptr[n], end = rowptr[n+1];
    int es = lane >> 1, cg = lane & 1;
    float a[8] = {0.f,0.f,0.f,0.f,0.f,0.f,0.f,0.f};
    float z = 0.f;
    for (int k = base + es; k < end; k += 32){
        int2 cp = csrp[k];
        float pv = __int_as_float(cp.y);
        z += pv;
        uint4 hv = *(const uint4*)(h2b + (size_t)cp.x*16 + cg*8);
        a[0] = fmaf(pv, __uint_as_float(hv.x << 16),          a[0]);
        a[1] = fmaf(pv, __uint_as_float(hv.x & 0xffff0000u),  a[1]);
        a[2] = fmaf(pv, __uint_as_float(hv.y << 16),          a[2]);
        a[3] = fmaf(pv, __uint_as_float(hv.y & 0xffff0000u),  a[3]);
        a[4] = fmaf(pv, __uint_as_float(hv.z << 16),          a[4]);
        a[5] = fmaf(pv, __uint_as_float(hv.z & 0xffff0000u),  a[5]);
        a[6] = fmaf(pv, __uint_as_float(hv.w << 16),          a[6]);
        a[7] = fmaf(pv, __uint_as_float(hv.w & 0xffff0000u),  a[7]);
    }
    #pragma unroll
    for (int m = 2; m <= 32; m <<= 1){
        #pragma unroll
        for (int j = 0; j < 8; ++j) a[j] += __shfl_xor(a[j], m);
        z += __shfl_xor(z, m);
    }
    float zi = 1.f/(z + 1e-16f);
    const float4 b0 = *(const float4*)(b2 + cg*8);
    const float4 b4 = *(const float4*)(b2 + cg*8 + 4);
    float o[8];
    o[0]=a[0]*zi+b0.x; o[1]=a[1]*zi+b0.y; o[2]=a[2]*zi+b0.z; o[3]=a[3]*zi+b0.w;
    o[4]=a[4]*zi+b4.x; o[5]=a[5]*zi+b4.y; o[6]=a[6]*zi+b4.z; o[7]=a[7]*zi+b4.w;
    float mx = o[0];
    #pragma unroll
    for (int j = 1; j < 8; ++j) mx = fmaxf(mx, o[j]);
    mx = fmaxf(mx, __shfl_xor(mx, 1));
    float sum = 0.f;
    #pragma unroll
    for (int j = 0; j < 8; ++j) sum += expf(o[j] - mx);
    sum += __shfl_xor(sum, 1);
    if (es == 0){
        float ls = logf(sum);
        float* op = out + (size_t)n*16 + cg*8;
        *(float4*)op     = make_float4(o[0]-mx-ls, o[1]-mx-ls, o[2]-mx-ls, o[3]-mx-ls);
        *(float4*)(op+4) = make_float4(o[4]-mx-ls, o[5]-mx-ls, o[6]-mx-ls, o[7]-mx-ls);
    }
}

extern "C" void kernel_launch(void* const* d_in, const int* in_sizes, int n_in,
                              void* d_out, int out_size, void* d_ws, size_t ws_size,
                              hipStream_t stream)
{
    const float* x      = (const float*)d_in[0];
    const int*   ei     = (const int*)d_in[1];
    const float* W1     = (const float*)d_in[2];
    const float* a_src1 = (const float*)d_in[3];
    const float* a_dst1 = (const float*)d_in[4];
    const float* b1     = (const float*)d_in[5];
    const float* W2     = (const float*)d_in[6];
    const float* a_src2 = (const float*)d_in[7];
    const float* a_dst2 = (const float*)d_in[8];
    const float* b2     = (const float*)d_in[9];
    float* out = (float*)d_out;
    const int N  = in_sizes[0] / 128;
    const int E  = in_sizes[1] / 2;
    const int ET = E + N;

    char* ptr = (char*)d_ws;
    auto alloc = [&](size_t bytes)->char* {
        char* r = ptr; ptr += (bytes + 255) & ~(size_t)255; return r;
    };
    unsigned short* h1b    = (unsigned short*)alloc((size_t)N*64*2);
    unsigned short* h2b    = (unsigned short*)alloc((size_t)N*16*2);
    float*          out1   = (float*)alloc((size_t)N*64*4);
    float*          s1     = (float*)alloc((size_t)N*4);
    float*          d1     = (float*)alloc((size_t)N*4);
    float*          s2     = (float*)alloc((size_t)N*4);
    float*          d2v    = (float*)alloc((size_t)N*4);
    int*            cnt    = (int*)alloc((size_t)N*4);
    int*            rowptr = (int*)alloc((size_t)(N+1)*4);
    int*            rank   = (int*)alloc((size_t)(ET+3)*4);
    int2*           csrp   = (int2*)alloc((size_t)ET*8);
    int*            bsum   = (int*)alloc(4096);

    const int gET  = (ET + 255)/256;
    const int gET4 = ((ET+3)/4 + 255)/256;
    const int nb1  = (N + 1023)/1024;
    const int nbN4 = (N + 3)/4;
    const int gN16 = ((size_t)N*16 + 255)/256;
    const int gG1  = (N + 63)/64;

    // CSR slot assignment: one ILP-4 atomic pass + scan
    hipMemsetAsync(cnt, 0, (size_t)N*4, stream);
    k_rank<<<gET4, 256, 0, stream>>>(ei, cnt, rank, E, ET);
    k_scan1<<<nb1, 256, 0, stream>>>(cnt, bsum, N);
    k_scan2<<<1, 64, 0, stream>>>(bsum, nb1);
    k_scan3<<<nb1, 256, 0, stream>>>(cnt, bsum, rowptr, N);

    // layer 1
    g1<<<gG1, 256, 0, stream>>>(x, W1, a_src1, a_dst1, h1b, s1, d1, N);
    k_score<<<gET, 256, 0, stream>>>(ei, rank, rowptr, s1, d1, csrp, E, ET);
    a1<<<nbN4, 256, 0, stream>>>(rowptr, csrp, h1b, b1, out1, N);

    // layer 2
    g2<<<gN16, 256, 0, stream>>>(out1, W2, a_src2, a_dst2, h2b, s2, d2v, N);
    k_score<<<gET, 256, 0, stream>>>(ei, rank, rowptr, s2, d2v, csrp, E, ET);
    a2<<<nbN4, 256, 0, stream>>>(rowptr, csrp, h2b, b2, out, N);
}

// Round 11
// 428.706 us; speedup vs baseline: 1.0463x; 1.0463x over previous
//
#include <hip/hip_runtime.h>
#include <math.h>

#define NEG 0.2f

__device__ __forceinline__ float leaky(float x){ return x >= 0.f ? x : NEG*x; }

__device__ __forceinline__ unsigned short f2b(float f){
    unsigned u = __float_as_uint(f);
    unsigned r = u + 0x7fffu + ((u >> 16) & 1u);
    return (unsigned short)(r >> 16);
}

// ---------------- fused: g1 register-tile GEMM + k_rank atomic pass --------
// blocks < gG1 compute a 64-row GEMM tile first; ALL blocks then run one
// ILP-4 rank chunk. Rank-only blocks start at t=0 and keep the (chip-level)
// atomic RMW pipeline saturated while GEMM blocks do FMA work.
__global__ __launch_bounds__(256) void rg1(const float* __restrict__ x,
        const float* __restrict__ W1, const float* __restrict__ a_src,
        const float* __restrict__ a_dst, unsigned short* __restrict__ h1b,
        float* __restrict__ s1, float* __restrict__ d1, int N,
        const int* __restrict__ ei, int* __restrict__ cnt,
        int* __restrict__ rank, int E, int ET)
{
    __shared__ float xsh[64][132];
    __shared__ float wsh[128][64];
    const int tid = threadIdx.x;
    const int gG1 = (N + 63) >> 6;
    if ((int)blockIdx.x < gG1) {
        const int rowbase = blockIdx.x * 64;
        #pragma unroll
        for (int i = 0; i < 8; ++i){
            int g = tid + i*256;
            ((float4*)&wsh[0][0])[g] = ((const float4*)W1)[g];
        }
        #pragma unroll
        for (int i = 0; i < 8; ++i){
            int g = tid + i*256;
            int r = g >> 5, c4 = g & 31;
            int grow = rowbase + r;
            float4 v = make_float4(0.f,0.f,0.f,0.f);
            if (grow < N) v = ((const float4*)(x + (size_t)grow*128))[c4];
            *(float4*)&xsh[r][c4*4] = v;
        }
        __syncthreads();
        const int tx = tid & 15, ty = tid >> 4;
        float acc[4][4];
        #pragma unroll
        for (int j=0;j<4;++j){
            #pragma unroll
            for (int c=0;c<4;++c) acc[j][c]=0.f;
        }
        #pragma unroll 4
        for (int k4 = 0; k4 < 32; ++k4){
            float4 xv[4], wv[4];
            #pragma unroll
            for (int j=0;j<4;++j) xv[j] = *(const float4*)&xsh[ty*4+j][k4*4];
            #pragma unroll
            for (int i=0;i<4;++i) wv[i] = *(const float4*)&wsh[k4*4+i][tx*4];
            #pragma unroll
            for (int j=0;j<4;++j){
                float x0=xv[j].x, x1=xv[j].y, x2=xv[j].z, x3=xv[j].w;
                acc[j][0]=fmaf(x0,wv[0].x,acc[j][0]); acc[j][1]=fmaf(x0,wv[0].y,acc[j][1]);
                acc[j][2]=fmaf(x0,wv[0].z,acc[j][2]); acc[j][3]=fmaf(x0,wv[0].w,acc[j][3]);
                acc[j][0]=fmaf(x1,wv[1].x,acc[j][0]); acc[j][1]=fmaf(x1,wv[1].y,acc[j][1]);
                acc[j][2]=fmaf(x1,wv[1].z,acc[j][2]); acc[j][3]=fmaf(x1,wv[1].w,acc[j][3]);
                acc[j][0]=fmaf(x2,wv[2].x,acc[j][0]); acc[j][1]=fmaf(x2,wv[2].y,acc[j][1]);
                acc[j][2]=fmaf(x2,wv[2].z,acc[j][2]); acc[j][3]=fmaf(x2,wv[2].w,acc[j][3]);
                acc[j][0]=fmaf(x3,wv[3].x,acc[j][0]); acc[j][1]=fmaf(x3,wv[3].y,acc[j][1]);
                acc[j][2]=fmaf(x3,wv[3].z,acc[j][2]); acc[j][3]=fmaf(x3,wv[3].w,acc[j][3]);
            }
        }
        const float4 asv = *(const float4*)&a_src[tx*4];
        const float4 adv = *(const float4*)&a_dst[tx*4];
        #pragma unroll
        for (int j=0;j<4;++j){
            int r = rowbase + ty*4 + j;
            float sv = acc[j][0]*asv.x + acc[j][1]*asv.y + acc[j][2]*asv.z + acc[j][3]*asv.w;
            float dv = acc[j][0]*adv.x + acc[j][1]*adv.y + acc[j][2]*adv.z + acc[j][3]*adv.w;
            #pragma unroll
            for (int dd=8; dd>0; dd>>=1){ sv += __shfl_xor(sv, dd, 16); dv += __shfl_xor(dv, dd, 16); }
            if (r < N){
                uint2 pk;
                pk.x = (unsigned)f2b(acc[j][0]) | ((unsigned)f2b(acc[j][1]) << 16);
                pk.y = (unsigned)f2b(acc[j][2]) | ((unsigned)f2b(acc[j][3]) << 16);
                *(uint2*)&h1b[(size_t)r*64 + tx*4] = pk;
                if (tx == 0){ s1[r] = sv; d1[r] = dv; }
            }
        }
    }
    // ---- rank chunk (all blocks) ----
    int i0 = (blockIdx.x*256 + tid)*4;
    if (i0 >= ET) return;
    int4 r4;
    if (i0 + 3 < E){
        int4 d4 = *(const int4*)(ei + E + i0);
        r4.x = atomicAdd(&cnt[d4.x], 1);
        r4.y = atomicAdd(&cnt[d4.y], 1);
        r4.z = atomicAdd(&cnt[d4.z], 1);
        r4.w = atomicAdd(&cnt[d4.w], 1);
    } else {
        #pragma unroll
        for (int u = 0; u < 4; ++u){
            int i = i0 + u;
            int dst = (i < E) ? ei[E + i] : (i - E);
            ((int*)&r4)[u] = atomicAdd(&cnt[dst], 1);
        }
    }
    *(int4*)(rank + i0) = r4;
}

__global__ void k_scan1(const int* __restrict__ cnt, int* __restrict__ bsum, int n){
    __shared__ int sh[256];
    int b = blockIdx.x, tid = threadIdx.x;
    int start = b*1024, s = 0;
    for (int i = tid; i < 1024; i += 256){ int idx = start+i; s += (idx<n)?cnt[idx]:0; }
    sh[tid]=s; __syncthreads();
    for (int d=128; d>0; d>>=1){ if (tid<d) sh[tid]+=sh[tid+d]; __syncthreads(); }
    if (tid==0) bsum[b]=sh[0];
}
__global__ void k_scan2(int* bsum, int nb){
    if (threadIdx.x==0 && blockIdx.x==0){
        int run=0;
        for (int i=0;i<nb;i++){ int v=bsum[i]; bsum[i]=run; run+=v; }
    }
}
__global__ void k_scan3(const int* __restrict__ cnt, const int* __restrict__ bsum,
                        int* __restrict__ rowptr, int n){
    __shared__ int sh[256];
    int b = blockIdx.x, tid = threadIdx.x;
    int i0 = b*1024 + tid*4;
    int v[4]; int local=0;
    #pragma unroll
    for (int k=0;k<4;k++){ int idx=i0+k; v[k]=(idx<n)?cnt[idx]:0; local+=v[k]; }
    sh[tid]=local; __syncthreads();
    for (int d=1; d<256; d<<=1){
        int t = (tid>=d)? sh[tid-d] : 0;
        __syncthreads();
        sh[tid] += t;
        __syncthreads();
    }
    int off = bsum[b] + sh[tid] - local;
    #pragma unroll
    for (int k=0;k<4;k++){
        int idx = i0+k;
        if (idx < n){
            rowptr[idx]=off; off += v[k];
            if (idx==n-1) rowptr[n]=off;
        }
    }
}

// ---------------- score: edge-parallel p = exp(leaky(s[src]+d[dst])),
// packed {src, p_bits} scattered into CSR slot rowptr[dst]+rank[i].
__global__ void k_score(const int* __restrict__ ei, const int* __restrict__ rank,
                        const int* __restrict__ rowptr,
                        const float* __restrict__ s, const float* __restrict__ d,
                        int2* __restrict__ csrp, int E, int ET){
    int i = blockIdx.x*256 + threadIdx.x;
    if (i >= ET) return;
    int src = (i < E) ? ei[i]     : (i - E);
    int dst = (i < E) ? ei[E + i] : (i - E);
    float pv = expf(leaky(s[src] + d[dst]));
    csrp[rowptr[dst] + rank[i]] = make_int2(src, __float_as_int(pv));
}

// ---------------- a1: aggregate layer 1, 8 edge-slots x 8 channel-groups ---
__global__ __launch_bounds__(256) void a1(const int* __restrict__ rowptr,
        const int2* __restrict__ csrp, const unsigned short* __restrict__ h1b,
        const float* __restrict__ b1, float* __restrict__ out1, int N)
{
    int wid = threadIdx.x>>6, lane = threadIdx.x&63;
    int n = blockIdx.x*4 + wid;
    if (n >= N) return;
    int base = rowptr[n], end = rowptr[n+1];
    int es = lane >> 3, cg = lane & 7;
    float a0=0.f,a1v=0.f,a2v=0.f,a3=0.f,a4=0.f,a5=0.f,a6=0.f,a7=0.f;
    float z = 0.f;
    for (int k = base + es; k < end; k += 8){
        int2 cp = csrp[k];
        float pv = __int_as_float(cp.y);
        z += pv;
        uint4 hv = *(const uint4*)(h1b + (size_t)cp.x*64 + cg*8);
        a0 = fmaf(pv, __uint_as_float(hv.x << 16),          a0);
        a1v= fmaf(pv, __uint_as_float(hv.x & 0xffff0000u),  a1v);
        a2v= fmaf(pv, __uint_as_float(hv.y << 16),          a2v);
        a3 = fmaf(pv, __uint_as_float(hv.y & 0xffff0000u),  a3);
        a4 = fmaf(pv, __uint_as_float(hv.z << 16),          a4);
        a5 = fmaf(pv, __uint_as_float(hv.z & 0xffff0000u),  a5);
        a6 = fmaf(pv, __uint_as_float(hv.w << 16),          a6);
        a7 = fmaf(pv, __uint_as_float(hv.w & 0xffff0000u),  a7);
    }
    #pragma unroll
    for (int m = 8; m <= 32; m <<= 1){
        a0 += __shfl_xor(a0, m); a1v += __shfl_xor(a1v, m);
        a2v += __shfl_xor(a2v, m); a3 += __shfl_xor(a3, m);
        a4 += __shfl_xor(a4, m); a5 += __shfl_xor(a5, m);
        a6 += __shfl_xor(a6, m); a7 += __shfl_xor(a7, m);
        z  += __shfl_xor(z, m);
    }
    if (es == 0){
        float zi = 1.f/(z + 1e-16f);
        const float4 b0 = *(const float4*)(b1 + cg*8);
        const float4 b4 = *(const float4*)(b1 + cg*8 + 4);
        float4 o0 = make_float4(fmaxf(a0*zi + b0.x, 0.f), fmaxf(a1v*zi + b0.y, 0.f),
                                fmaxf(a2v*zi + b0.z, 0.f), fmaxf(a3*zi + b0.w, 0.f));
        float4 o4 = make_float4(fmaxf(a4*zi + b4.x, 0.f), fmaxf(a5*zi + b4.y, 0.f),
                                fmaxf(a6*zi + b4.z, 0.f), fmaxf(a7*zi + b4.w, 0.f));
        float* op = out1 + (size_t)n*64 + cg*8;
        *(float4*)op = o0;
        *(float4*)(op+4) = o4;
    }
}

// ---------------- g2: h2b(bf16) = out1 @ W2; s2; d2 ------------------------
__global__ __launch_bounds__(256) void g2(const float* __restrict__ xin,
        const float* __restrict__ W2, const float* __restrict__ a_src,
        const float* __restrict__ a_dst, unsigned short* __restrict__ h2b,
        float* __restrict__ s2, float* __restrict__ d2, int N)
{
    __shared__ float w[64*16];
    const int tid = threadIdx.x;
    for (int k = tid; k < 64*16/4; k += 256)
        ((float4*)w)[k] = ((const float4*)W2)[k];
    __syncthreads();
    int idx = blockIdx.x*256 + tid;
    int n = idx >> 4, c = idx & 15;
    if (n >= N) return;
    const float as = a_src[c], ad = a_dst[c];
    const float4* xr = (const float4*)(xin + (size_t)n*64);
    float acc = 0.f;
    #pragma unroll
    for (int i4 = 0; i4 < 16; ++i4) {
        float4 v = xr[i4];
        acc = fmaf(v.x, w[(i4*4+0)*16 + c], acc);
        acc = fmaf(v.y, w[(i4*4+1)*16 + c], acc);
        acc = fmaf(v.z, w[(i4*4+2)*16 + c], acc);
        acc = fmaf(v.w, w[(i4*4+3)*16 + c], acc);
    }
    h2b[(size_t)n*16 + c] = f2b(acc);
    float sv = acc*as, dv = acc*ad;
    #pragma unroll
    for (int dd = 8; dd > 0; dd >>= 1){ sv += __shfl_xor(sv, dd, 16); dv += __shfl_xor(dv, dd, 16); }
    if (c == 0) { s2[n] = sv; d2[n] = dv; }
}

// ---------------- a2: aggregate layer 2 + log_softmax ----------------------
__global__ __launch_bounds__(256) void a2(const int* __restrict__ rowptr,
        const int2* __restrict__ csrp, const unsigned short* __restrict__ h2b,
        const float* __restrict__ b2, float* __restrict__ out, int N)
{
    int wid = threadIdx.x>>6, lane = threadIdx.x&63;
    int n = blockIdx.x*4 + wid;
    if (n >= N) return;
    int base = rowptr[n], end = rowptr[n+1];
    int es = lane >> 1, cg = lane & 1;
    float a[8] = {0.f,0.f,0.f,0.f,0.f,0.f,0.f,0.f};
    float z = 0.f;
    for (int k = base + es; k < end; k += 32){
        int2 cp = csrp[k];
        float pv = __int_as_float(cp.y);
        z += pv;
        uint4 hv = *(const uint4*)(h2b + (size_t)cp.x*16 + cg*8);
        a[0] = fmaf(pv, __uint_as_float(hv.x << 16),          a[0]);
        a[1] = fmaf(pv, __uint_as_float(hv.x & 0xffff0000u),  a[1]);
        a[2] = fmaf(pv, __uint_as_float(hv.y << 16),          a[2]);
        a[3] = fmaf(pv, __uint_as_float(hv.y & 0xffff0000u),  a[3]);
        a[4] = fmaf(pv, __uint_as_float(hv.z << 16),          a[4]);
        a[5] = fmaf(pv, __uint_as_float(hv.z & 0xffff0000u),  a[5]);
        a[6] = fmaf(pv, __uint_as_float(hv.w << 16),          a[6]);
        a[7] = fmaf(pv, __uint_as_float(hv.w & 0xffff0000u),  a[7]);
    }
    #pragma unroll
    for (int m = 2; m <= 32; m <<= 1){
        #pragma unroll
        for (int j = 0; j < 8; ++j) a[j] += __shfl_xor(a[j], m);
        z += __shfl_xor(z, m);
    }
    float zi = 1.f/(z + 1e-16f);
    const float4 b0 = *(const float4*)(b2 + cg*8);
    const float4 b4 = *(const float4*)(b2 + cg*8 + 4);
    float o[8];
    o[0]=a[0]*zi+b0.x; o[1]=a[1]*zi+b0.y; o[2]=a[2]*zi+b0.z; o[3]=a[3]*zi+b0.w;
    o[4]=a[4]*zi+b4.x; o[5]=a[5]*zi+b4.y; o[6]=a[6]*zi+b4.z; o[7]=a[7]*zi+b4.w;
    float mx = o[0];
    #pragma unroll
    for (int j = 1; j < 8; ++j) mx = fmaxf(mx, o[j]);
    mx = fmaxf(mx, __shfl_xor(mx, 1));
    float sum = 0.f;
    #pragma unroll
    for (int j = 0; j < 8; ++j) sum += expf(o[j] - mx);
    sum += __shfl_xor(sum, 1);
    if (es == 0){
        float ls = logf(sum);
        float* op = out + (size_t)n*16 + cg*8;
        *(float4*)op     = make_float4(o[0]-mx-ls, o[1]-mx-ls, o[2]-mx-ls, o[3]-mx-ls);
        *(float4*)(op+4) = make_float4(o[4]-mx-ls, o[5]-mx-ls, o[6]-mx-ls, o[7]-mx-ls);
    }
}

extern "C" void kernel_launch(void* const* d_in, const int* in_sizes, int n_in,
                              void* d_out, int out_size, void* d_ws, size_t ws_size,
                              hipStream_t stream)
{
    const float* x      = (const float*)d_in[0];
    const int*   ei     = (const int*)d_in[1];
    const float* W1     = (const float*)d_in[2];
    const float* a_src1 = (const float*)d_in[3];
    const float* a_dst1 = (const float*)d_in[4];
    const float* b1     = (const float*)d_in[5];
    const float* W2     = (const float*)d_in[6];
    const float* a_src2 = (const float*)d_in[7];
    const float* a_dst2 = (const float*)d_in[8];
    const float* b2     = (const float*)d_in[9];
    float* out = (float*)d_out;
    const int N  = in_sizes[0] / 128;
    const int E  = in_sizes[1] / 2;
    const int ET = E + N;

    char* ptr = (char*)d_ws;
    auto alloc = [&](size_t bytes)->char* {
        char* r = ptr; ptr += (bytes + 255) & ~(size_t)255; return r;
    };
    unsigned short* h1b    = (unsigned short*)alloc((size_t)N*64*2);
    unsigned short* h2b    = (unsigned short*)alloc((size_t)N*16*2);
    float*          out1   = (float*)alloc((size_t)N*64*4);
    float*          s1     = (float*)alloc((size_t)N*4);
    float*          d1     = (float*)alloc((size_t)N*4);
    float*          s2     = (float*)alloc((size_t)N*4);
    float*          d2v    = (float*)alloc((size_t)N*4);
    int*            cnt    = (int*)alloc((size_t)N*4);
    int*            rowptr = (int*)alloc((size_t)(N+1)*4);
    int*            rank   = (int*)alloc((size_t)(ET+3)*4);
    int2*           csrp   = (int2*)alloc((size_t)ET*8);
    int*            bsum   = (int*)alloc(4096);

    const int gET  = (ET + 255)/256;
    const int gET4 = ((ET+3)/4 + 255)/256;
    const int nb1  = (N + 1023)/1024;
    const int nbN4 = (N + 3)/4;
    const int gN16 = ((size_t)N*16 + 255)/256;
    const int gG1  = (N + 63)/64;
    const int gRG1 = (gET4 > gG1) ? gET4 : gG1;

    // fused: g1 GEMM tiles + rank atomic pass (independent work overlapped)
    hipMemsetAsync(cnt, 0, (size_t)N*4, stream);
    rg1<<<gRG1, 256, 0, stream>>>(x, W1, a_src1, a_dst1, h1b, s1, d1, N,
                                  ei, cnt, rank, E, ET);
    k_scan1<<<nb1, 256, 0, stream>>>(cnt, bsum, N);
    k_scan2<<<1, 64, 0, stream>>>(bsum, nb1);
    k_scan3<<<nb1, 256, 0, stream>>>(cnt, bsum, rowptr, N);

    // layer 1
    k_score<<<gET, 256, 0, stream>>>(ei, rank, rowptr, s1, d1, csrp, E, ET);
    a1<<<nbN4, 256, 0, stream>>>(rowptr, csrp, h1b, b1, out1, N);

    // layer 2
    g2<<<gN16, 256, 0, stream>>>(out1, W2, a_src2, a_dst2, h2b, s2, d2v, N);
    k_score<<<gET, 256, 0, stream>>>(ei, rank, rowptr, s2, d2v, csrp, E, ET);
    a2<<<nbN4, 256, 0, stream>>>(rowptr, csrp, h2b, b2, out, N);
}

// Round 12
// 415.996 us; speedup vs baseline: 1.0783x; 1.0306x over previous
//
#include <hip/hip_runtime.h>
#include <math.h>

#define NEG 0.2f

__device__ __forceinline__ float leaky(float x){ return x >= 0.f ? x : NEG*x; }

__device__ __forceinline__ unsigned short f2b(float f){
    unsigned u = __float_as_uint(f);
    unsigned r = u + 0x7fffu + ((u >> 16) & 1u);
    return (unsigned short)(r >> 16);
}

// ---------------- fused: g1 register-tile GEMM + k_rank atomic pass --------
// W1 in LDS (32KB only); x read directly per k4 step (16-lane broadcast,
// L1-resident) -> 4-5 blocks/CU so rank-only blocks keep atomic pipe fed.
__global__ __launch_bounds__(256) void rg1(const float* __restrict__ x,
        const float* __restrict__ W1, const float* __restrict__ a_src,
        const float* __restrict__ a_dst, unsigned short* __restrict__ h1b,
        float* __restrict__ s1, float* __restrict__ d1, int N,
        const int* __restrict__ ei, int* __restrict__ cnt,
        int* __restrict__ rank, int E, int ET)
{
    __shared__ float wsh[128][64];
    const int tid = threadIdx.x;
    const int gG1 = (N + 63) >> 6;
    if ((int)blockIdx.x < gG1) {
        const int rowbase = blockIdx.x * 64;
        #pragma unroll
        for (int i = 0; i < 8; ++i){
            int g = tid + i*256;
            ((float4*)&wsh[0][0])[g] = ((const float4*)W1)[g];
        }
        __syncthreads();
        const int tx = tid & 15, ty = tid >> 4;
        const int r0 = rowbase + ty*4;
        const float4* xr0 = (const float4*)(x + (size_t)min(r0+0, N-1)*128);
        const float4* xr1 = (const float4*)(x + (size_t)min(r0+1, N-1)*128);
        const float4* xr2 = (const float4*)(x + (size_t)min(r0+2, N-1)*128);
        const float4* xr3 = (const float4*)(x + (size_t)min(r0+3, N-1)*128);
        float acc[4][4];
        #pragma unroll
        for (int j=0;j<4;++j){
            #pragma unroll
            for (int c=0;c<4;++c) acc[j][c]=0.f;
        }
        #pragma unroll 4
        for (int k4 = 0; k4 < 32; ++k4){
            float4 xv[4], wv[4];
            xv[0] = xr0[k4]; xv[1] = xr1[k4]; xv[2] = xr2[k4]; xv[3] = xr3[k4];
            #pragma unroll
            for (int i=0;i<4;++i) wv[i] = *(const float4*)&wsh[k4*4+i][tx*4];
            #pragma unroll
            for (int j=0;j<4;++j){
                float x0=xv[j].x, x1=xv[j].y, x2=xv[j].z, x3=xv[j].w;
                acc[j][0]=fmaf(x0,wv[0].x,acc[j][0]); acc[j][1]=fmaf(x0,wv[0].y,acc[j][1]);
                acc[j][2]=fmaf(x0,wv[0].z,acc[j][2]); acc[j][3]=fmaf(x0,wv[0].w,acc[j][3]);
                acc[j][0]=fmaf(x1,wv[1].x,acc[j][0]); acc[j][1]=fmaf(x1,wv[1].y,acc[j][1]);
                acc[j][2]=fmaf(x1,wv[1].z,acc[j][2]); acc[j][3]=fmaf(x1,wv[1].w,acc[j][3]);
                acc[j][0]=fmaf(x2,wv[2].x,acc[j][0]); acc[j][1]=fmaf(x2,wv[2].y,acc[j][1]);
                acc[j][2]=fmaf(x2,wv[2].z,acc[j][2]); acc[j][3]=fmaf(x2,wv[2].w,acc[j][3]);
                acc[j][0]=fmaf(x3,wv[3].x,acc[j][0]); acc[j][1]=fmaf(x3,wv[3].y,acc[j][1]);
                acc[j][2]=fmaf(x3,wv[3].z,acc[j][2]); acc[j][3]=fmaf(x3,wv[3].w,acc[j][3]);
            }
        }
        const float4 asv = *(const float4*)&a_src[tx*4];
        const float4 adv = *(const float4*)&a_dst[tx*4];
        #pragma unroll
        for (int j=0;j<4;++j){
            int r = rowbase + ty*4 + j;
            float sv = acc[j][0]*asv.x + acc[j][1]*asv.y + acc[j][2]*asv.z + acc[j][3]*asv.w;
            float dv = acc[j][0]*adv.x + acc[j][1]*adv.y + acc[j][2]*adv.z + acc[j][3]*adv.w;
            #pragma unroll
            for (int dd=8; dd>0; dd>>=1){ sv += __shfl_xor(sv, dd, 16); dv += __shfl_xor(dv, dd, 16); }
            if (r < N){
                uint2 pk;
                pk.x = (unsigned)f2b(acc[j][0]) | ((unsigned)f2b(acc[j][1]) << 16);
                pk.y = (unsigned)f2b(acc[j][2]) | ((unsigned)f2b(acc[j][3]) << 16);
                *(uint2*)&h1b[(size_t)r*64 + tx*4] = pk;
                if (tx == 0){ s1[r] = sv; d1[r] = dv; }
            }
        }
    }
    // ---- rank chunk (all blocks) ----
    int i0 = (blockIdx.x*256 + tid)*4;
    if (i0 >= ET) return;
    int4 r4;
    if (i0 + 3 < E){
        int4 d4 = *(const int4*)(ei + E + i0);
        r4.x = atomicAdd(&cnt[d4.x], 1);
        r4.y = atomicAdd(&cnt[d4.y], 1);
        r4.z = atomicAdd(&cnt[d4.z], 1);
        r4.w = atomicAdd(&cnt[d4.w], 1);
    } else {
        #pragma unroll
        for (int u = 0; u < 4; ++u){
            int i = i0 + u;
            int dst = (i < E) ? ei[E + i] : (i - E);
            ((int*)&r4)[u] = atomicAdd(&cnt[dst], 1);
        }
    }
    *(int4*)(rank + i0) = r4;
}

__global__ void k_scan1(const int* __restrict__ cnt, int* __restrict__ bsum, int n){
    __shared__ int sh[256];
    int b = blockIdx.x, tid = threadIdx.x;
    int start = b*1024, s = 0;
    for (int i = tid; i < 1024; i += 256){ int idx = start+i; s += (idx<n)?cnt[idx]:0; }
    sh[tid]=s; __syncthreads();
    for (int d=128; d>0; d>>=1){ if (tid<d) sh[tid]+=sh[tid+d]; __syncthreads(); }
    if (tid==0) bsum[b]=sh[0];
}
// scan3 with inlined bsum prefix (replaces scan2+scan3)
__global__ void k_scan3(const int* __restrict__ cnt, const int* __restrict__ bsum,
                        int* __restrict__ rowptr, int n){
    __shared__ int sh[256];
    __shared__ int basesh;
    int b = blockIdx.x, tid = threadIdx.x;
    int pb = 0;
    for (int i = tid; i < b; i += 256) pb += bsum[i];
    sh[tid] = pb; __syncthreads();
    for (int d=128; d>0; d>>=1){ if (tid<d) sh[tid]+=sh[tid+d]; __syncthreads(); }
    if (tid==0) basesh = sh[0];
    __syncthreads();
    int base = basesh;
    __syncthreads();
    int i0 = b*1024 + tid*4;
    int v[4]; int local=0;
    #pragma unroll
    for (int k=0;k<4;k++){ int idx=i0+k; v[k]=(idx<n)?cnt[idx]:0; local+=v[k]; }
    sh[tid]=local; __syncthreads();
    for (int d=1; d<256; d<<=1){
        int t = (tid>=d)? sh[tid-d] : 0;
        __syncthreads();
        sh[tid] += t;
        __syncthreads();
    }
    int off = base + sh[tid] - local;
    #pragma unroll
    for (int k=0;k<4;k++){
        int idx = i0+k;
        if (idx < n){
            rowptr[idx]=off; off += v[k];
            if (idx==n-1) rowptr[n]=off;
        }
    }
}

// ---------------- score: edge-parallel p = exp(leaky(s[src]+d[dst])),
// packed {src, p_bits} scattered into CSR slot rowptr[dst]+rank[i].
__global__ void k_score(const int* __restrict__ ei, const int* __restrict__ rank,
                        const int* __restrict__ rowptr,
                        const float* __restrict__ s, const float* __restrict__ d,
                        int2* __restrict__ csrp, int E, int ET){
    int i = blockIdx.x*256 + threadIdx.x;
    if (i >= ET) return;
    int src = (i < E) ? ei[i]     : (i - E);
    int dst = (i < E) ? ei[E + i] : (i - E);
    float pv = expf(leaky(s[src] + d[dst]));
    csrp[rowptr[dst] + rank[i]] = make_int2(src, __float_as_int(pv));
}

// ---------------- a1: aggregate layer 1, 8 edge-slots x 8 channel-groups ---
__global__ __launch_bounds__(256) void a1(const int* __restrict__ rowptr,
        const int2* __restrict__ csrp, const unsigned short* __restrict__ h1b,
        const float* __restrict__ b1, float* __restrict__ out1, int N)
{
    int wid = threadIdx.x>>6, lane = threadIdx.x&63;
    int n = blockIdx.x*4 + wid;
    if (n >= N) return;
    int base = rowptr[n], end = rowptr[n+1];
    int es = lane >> 3, cg = lane & 7;
    float a0=0.f,a1v=0.f,a2v=0.f,a3=0.f,a4=0.f,a5=0.f,a6=0.f,a7=0.f;
    float z = 0.f;
    for (int k = base + es; k < end; k += 8){
        int2 cp = csrp[k];
        float pv = __int_as_float(cp.y);
        z += pv;
        uint4 hv = *(const uint4*)(h1b + (size_t)cp.x*64 + cg*8);
        a0 = fmaf(pv, __uint_as_float(hv.x << 16),          a0);
        a1v= fmaf(pv, __uint_as_float(hv.x & 0xffff0000u),  a1v);
        a2v= fmaf(pv, __uint_as_float(hv.y << 16),          a2v);
        a3 = fmaf(pv, __uint_as_float(hv.y & 0xffff0000u),  a3);
        a4 = fmaf(pv, __uint_as_float(hv.z << 16),          a4);
        a5 = fmaf(pv, __uint_as_float(hv.z & 0xffff0000u),  a5);
        a6 = fmaf(pv, __uint_as_float(hv.w << 16),          a6);
        a7 = fmaf(pv, __uint_as_float(hv.w & 0xffff0000u),  a7);
    }
    #pragma unroll
    for (int m = 8; m <= 32; m <<= 1){
        a0 += __shfl_xor(a0, m); a1v += __shfl_xor(a1v, m);
        a2v += __shfl_xor(a2v, m); a3 += __shfl_xor(a3, m);
        a4 += __shfl_xor(a4, m); a5 += __shfl_xor(a5, m);
        a6 += __shfl_xor(a6, m); a7 += __shfl_xor(a7, m);
        z  += __shfl_xor(z, m);
    }
    if (es == 0){
        float zi = 1.f/(z + 1e-16f);
        const float4 b0 = *(const float4*)(b1 + cg*8);
        const float4 b4 = *(const float4*)(b1 + cg*8 + 4);
        float4 o0 = make_float4(fmaxf(a0*zi + b0.x, 0.f), fmaxf(a1v*zi + b0.y, 0.f),
                                fmaxf(a2v*zi + b0.z, 0.f), fmaxf(a3*zi + b0.w, 0.f));
        float4 o4 = make_float4(fmaxf(a4*zi + b4.x, 0.f), fmaxf(a5*zi + b4.y, 0.f),
                                fmaxf(a6*zi + b4.z, 0.f), fmaxf(a7*zi + b4.w, 0.f));
        float* op = out1 + (size_t)n*64 + cg*8;
        *(float4*)op = o0;
        *(float4*)(op+4) = o4;
    }
}

// ---------------- g2: h2b(bf16) = out1 @ W2; s2; d2 ------------------------
__global__ __launch_bounds__(256) void g2(const float* __restrict__ xin,
        const float* __restrict__ W2, const float* __restrict__ a_src,
        const float* __restrict__ a_dst, unsigned short* __restrict__ h2b,
        float* __restrict__ s2, float* __restrict__ d2, int N)
{
    __shared__ float w[64*16];
    const int tid = threadIdx.x;
    for (int k = tid; k < 64*16/4; k += 256)
        ((float4*)w)[k] = ((const float4*)W2)[k];
    __syncthreads();
    int idx = blockIdx.x*256 + tid;
    int n = idx >> 4, c = idx & 15;
    if (n >= N) return;
    const float as = a_src[c], ad = a_dst[c];
    const float4* xr = (const float4*)(xin + (size_t)n*64);
    float acc = 0.f;
    #pragma unroll
    for (int i4 = 0; i4 < 16; ++i4) {
        float4 v = xr[i4];
        acc = fmaf(v.x, w[(i4*4+0)*16 + c], acc);
        acc = fmaf(v.y, w[(i4*4+1)*16 + c], acc);
        acc = fmaf(v.z, w[(i4*4+2)*16 + c], acc);
        acc = fmaf(v.w, w[(i4*4+3)*16 + c], acc);
    }
    h2b[(size_t)n*16 + c] = f2b(acc);
    float sv = acc*as, dv = acc*ad;
    #pragma unroll
    for (int dd = 8; dd > 0; dd >>= 1){ sv += __shfl_xor(sv, dd, 16); dv += __shfl_xor(dv, dd, 16); }
    if (c == 0) { s2[n] = sv; d2[n] = dv; }
}

// ---------------- a2: aggregate layer 2 + log_softmax ----------------------
__global__ __launch_bounds__(256) void a2(const int* __restrict__ rowptr,
        const int2* __restrict__ csrp, const unsigned short* __restrict__ h2b,
        const float* __restrict__ b2, float* __restrict__ out, int N)
{
    int wid = threadIdx.x>>6, lane = threadIdx.x&63;
    int n = blockIdx.x*4 + wid;
    if (n >= N) return;
    int base = rowptr[n], end = rowptr[n+1];
    int es = lane >> 1, cg = lane & 1;
    float a[8] = {0.f,0.f,0.f,0.f,0.f,0.f,0.f,0.f};
    float z = 0.f;
    for (int k = base + es; k < end; k += 32){
        int2 cp = csrp[k];
        float pv = __int_as_float(cp.y);
        z += pv;
        uint4 hv = *(const uint4*)(h2b + (size_t)cp.x*16 + cg*8);
        a[0] = fmaf(pv, __uint_as_float(hv.x << 16),          a[0]);
        a[1] = fmaf(pv, __uint_as_float(hv.x & 0xffff0000u),  a[1]);
        a[2] = fmaf(pv, __uint_as_float(hv.y << 16),          a[2]);
        a[3] = fmaf(pv, __uint_as_float(hv.y & 0xffff0000u),  a[3]);
        a[4] = fmaf(pv, __uint_as_float(hv.z << 16),          a[4]);
        a[5] = fmaf(pv, __uint_as_float(hv.z & 0xffff0000u),  a[5]);
        a[6] = fmaf(pv, __uint_as_float(hv.w << 16),          a[6]);
        a[7] = fmaf(pv, __uint_as_float(hv.w & 0xffff0000u),  a[7]);
    }
    #pragma unroll
    for (int m = 2; m <= 32; m <<= 1){
        #pragma unroll
        for (int j = 0; j < 8; ++j) a[j] += __shfl_xor(a[j], m);
        z += __shfl_xor(z, m);
    }
    float zi = 1.f/(z + 1e-16f);
    const float4 b0 = *(const float4*)(b2 + cg*8);
    const float4 b4 = *(const float4*)(b2 + cg*8 + 4);
    float o[8];
    o[0]=a[0]*zi+b0.x; o[1]=a[1]*zi+b0.y; o[2]=a[2]*zi+b0.z; o[3]=a[3]*zi+b0.w;
    o[4]=a[4]*zi+b4.x; o[5]=a[5]*zi+b4.y; o[6]=a[6]*zi+b4.z; o[7]=a[7]*zi+b4.w;
    float mx = o[0];
    #pragma unroll
    for (int j = 1; j < 8; ++j) mx = fmaxf(mx, o[j]);
    mx = fmaxf(mx, __shfl_xor(mx, 1));
    float sum = 0.f;
    #pragma unroll
    for (int j = 0; j < 8; ++j) sum += expf(o[j] - mx);
    sum += __shfl_xor(sum, 1);
    if (es == 0){
        float ls = logf(sum);
        float* op = out + (size_t)n*16 + cg*8;
        *(float4*)op     = make_float4(o[0]-mx-ls, o[1]-mx-ls, o[2]-mx-ls, o[3]-mx-ls);
        *(float4*)(op+4) = make_float4(o[4]-mx-ls, o[5]-mx-ls, o[6]-mx-ls, o[7]-mx-ls);
    }
}

extern "C" void kernel_launch(void* const* d_in, const int* in_sizes, int n_in,
                              void* d_out, int out_size, void* d_ws, size_t ws_size,
                              hipStream_t stream)
{
    const float* x      = (const float*)d_in[0];
    const int*   ei     = (const int*)d_in[1];
    const float* W1     = (const float*)d_in[2];
    const float* a_src1 = (const float*)d_in[3];
    const float* a_dst1 = (const float*)d_in[4];
    const float* b1     = (const float*)d_in[5];
    const float* W2     = (const float*)d_in[6];
    const float* a_src2 = (const float*)d_in[7];
    const float* a_dst2 = (const float*)d_in[8];
    const float* b2     = (const float*)d_in[9];
    float* out = (float*)d_out;
    const int N  = in_sizes[0] / 128;
    const int E  = in_sizes[1] / 2;
    const int ET = E + N;

    char* ptr = (char*)d_ws;
    auto alloc = [&](size_t bytes)->char* {
        char* r = ptr; ptr += (bytes + 255) & ~(size_t)255; return r;
    };
    unsigned short* h1b    = (unsigned short*)alloc((size_t)N*64*2);
    unsigned short* h2b    = (unsigned short*)alloc((size_t)N*16*2);
    float*          out1   = (float*)alloc((size_t)N*64*4);
    float*          s1     = (float*)alloc((size_t)N*4);
    float*          d1     = (float*)alloc((size_t)N*4);
    float*          s2     = (float*)alloc((size_t)N*4);
    float*          d2v    = (float*)alloc((size_t)N*4);
    int*            cnt    = (int*)alloc((size_t)N*4);
    int*            rowptr = (int*)alloc((size_t)(N+1)*4);
    int*            rank   = (int*)alloc((size_t)(ET+3)*4);
    int2*           csrp   = (int2*)alloc((size_t)ET*8);
    int*            bsum   = (int*)alloc(4096);

    const int gET  = (ET + 255)/256;
    const int gET4 = ((ET+3)/4 + 255)/256;
    const int nb1  = (N + 1023)/1024;
    const int nbN4 = (N + 3)/4;
    const int gN16 = ((size_t)N*16 + 255)/256;
    const int gG1  = (N + 63)/64;
    const int gRG1 = (gET4 > gG1) ? gET4 : gG1;

    // fused: g1 GEMM tiles + rank atomic pass (independent work overlapped)
    hipMemsetAsync(cnt, 0, (size_t)N*4, stream);
    rg1<<<gRG1, 256, 0, stream>>>(x, W1, a_src1, a_dst1, h1b, s1, d1, N,
                                  ei, cnt, rank, E, ET);
    k_scan1<<<nb1, 256, 0, stream>>>(cnt, bsum, N);
    k_scan3<<<nb1, 256, 0, stream>>>(cnt, bsum, rowptr, N);

    // layer 1
    k_score<<<gET, 256, 0, stream>>>(ei, rank, rowptr, s1, d1, csrp, E, ET);
    a1<<<nbN4, 256, 0, stream>>>(rowptr, csrp, h1b, b1, out1, N);

    // layer 2
    g2<<<gN16, 256, 0, stream>>>(out1, W2, a_src2, a_dst2, h2b, s2, d2v, N);
    k_score<<<gET, 256, 0, stream>>>(ei, rank, rowptr, s2, d2v, csrp, E, ET);
    a2<<<nbN4, 256, 0, stream>>>(rowptr, csrp, h2b, b2, out, N);
}